// Round 8
// baseline (506.541 us; speedup 1.0000x reference)
//
#include <hip/hip_runtime.h>
#include <hip/hip_bf16.h>

typedef __hip_bfloat16 bf16;
typedef short short8 __attribute__((ext_vector_type(8)));
typedef float f32x4 __attribute__((ext_vector_type(4)));

#define S_LEN 2048
#define NHEADS 16
#define NKVH 4
#define HDIM 128
#define QKVN 5120
#define EPS_F 1e-6f
#define NEG_INF -1e30f
// SCALE * log2(e): attention scores computed in base-2 domain
#define QSCALE 0.12751744f
// |score*log2e| <= sqrt(128)*sqrt(128)*SCALE*log2e = 16.33 -> fixed softmax max
#define FIXED_M 17.0f

#define KT2 128
// split point (in double-K-tiles of 128 keys) for the balanced split-K schedule
#define KSPLIT_D 8

__device__ __forceinline__ void async16(const bf16* g, bf16* l) {
  __builtin_amdgcn_global_load_lds(
      (const __attribute__((address_space(1))) void*)g,
      (__attribute__((address_space(3))) void*)l, 16, 0, 0);
}

__device__ __forceinline__ f32x4 mfma_bf16(short8 a, short8 b, f32x4 c) {
  return __builtin_amdgcn_mfma_f32_16x16x32_bf16(a, b, c, 0, 0, 0);
}

__device__ __forceinline__ float bfbits_to_f(short s) {
  unsigned u = ((unsigned)(unsigned short)s) << 16;
  return __uint_as_float(u);
}
__device__ __forceinline__ short f_to_bfbits(float f) {
  __hip_bfloat16 h = __float2bfloat16(f);
  return *reinterpret_cast<short*>(&h);
}

__device__ __forceinline__ void store_c(float* p, float v) { *p = v; }
__device__ __forceinline__ void store_c(bf16* p, float v) { *p = __float2bfloat16(v); }

// barrier + compiler memory fence (keep LDS reads from sliding above the barrier)
__device__ __forceinline__ void barrier_f() {
  __builtin_amdgcn_s_barrier();
  asm volatile("" ::: "memory");
}

// ---------------- fused prep: f32->bf16 cast of hs + 4 transposes, ONE launch ----------
__device__ __forceinline__ void do_transpose(const float* __restrict__ in,
                                             bf16* __restrict__ out, int N,
                                             int bx, int by, int t) {
  __shared__ float tile[32][33];
  const int H = 2048;
  int n0 = bx * 32, h0 = by * 32;
  int tx = t & 31, ty = t >> 5;
#pragma unroll
  for (int i = 0; i < 4; i++)
    tile[ty + i * 8][tx] = in[(long)(h0 + ty + i * 8) * N + n0 + tx];
  __syncthreads();
#pragma unroll
  for (int i = 0; i < 4; i++)
    out[(long)(n0 + ty + i * 8) * H + h0 + tx] = __float2bfloat16(tile[tx][ty + i * 8]);
}

__global__ __launch_bounds__(256) void prep_fused(const float* __restrict__ hs,
                                                  const float* __restrict__ wq,
                                                  const float* __restrict__ wk,
                                                  const float* __restrict__ wv,
                                                  const float* __restrict__ wo,
                                                  bf16* __restrict__ Xb,
                                                  bf16* __restrict__ WqkvT,
                                                  bf16* __restrict__ WoT) {
  const int bid = blockIdx.x;
  const int t = threadIdx.x;
  if (bid < 8192) {
    do_transpose(wq, WqkvT, 4096, bid & 127, bid >> 7, t);
  } else if (bid < 9216) {
    int l = bid - 8192;
    do_transpose(wk, WqkvT + 4096L * 2048, 512, l & 15, l >> 4, t);
  } else if (bid < 10240) {
    int l = bid - 9216;
    do_transpose(wv, WqkvT + 4608L * 2048, 512, l & 15, l >> 4, t);
  } else if (bid < 14336) {
    int l = bid - 10240;
    do_transpose(wo, WoT, 2048, l & 63, l >> 6, t);
  } else {
    int i = ((bid - 14336) * 256 + t) * 4;
    float4 v = *(const float4*)(hs + i);
    __hip_bfloat162 p0, p1;
    p0.x = __float2bfloat16(v.x); p0.y = __float2bfloat16(v.y);
    p1.x = __float2bfloat16(v.z); p1.y = __float2bfloat16(v.w);
    *(__hip_bfloat162*)(Xb + i) = p0;
    *(__hip_bfloat162*)(Xb + i + 2) = p1;
  }
}

// ---------------- tiled transpose + cast: in (H,N) f32 -> out (N,H) bf16 ----------------
__global__ __launch_bounds__(256) void transpose_cast(const float* __restrict__ in,
                                                      bf16* __restrict__ out, int H, int N,
                                                      long inBS, long outBS) {
  __shared__ float tile[32][33];
  const float* ip = in + (long)blockIdx.z * inBS;
  bf16* op = out + (long)blockIdx.z * outBS;
  int n0 = blockIdx.x * 32, h0 = blockIdx.y * 32;
  int tx = threadIdx.x, ty = threadIdx.y;
#pragma unroll
  for (int i = 0; i < 4; i++)
    tile[ty + i * 8][tx] = ip[(long)(h0 + ty + i * 8) * N + n0 + tx];
  __syncthreads();
#pragma unroll
  for (int i = 0; i < 4; i++)
    op[(long)(n0 + ty + i * 8) * H + h0 + tx] = __float2bfloat16(tile[tx][ty + i * 8]);
}

// ---------------- big-tile bt-form bf16 GEMM with counted-vmcnt pipeline ----------------
// (unchanged; verified at 1057 TF on the QKV shape)
template <typename CT, int BM, int BN, int B0, int B1, int B2, int B3>
__global__ __launch_bounds__(512, 2) void gemm_big(const bf16* __restrict__ A,
                                                   const bf16* __restrict__ BT,
                                                   CT* __restrict__ C, int K, int ldc) {
  constexpr int L = (BM + BN) / 64;    // global_load_lds per thread per K-tile
  constexpr int CA = BM * 8;           // A-chunks per tile (multiple of 512)
  constexpr int MRH = BM / 64;         // m-frags per half-phase
  constexpr int NR = BN / 64;          // n-frags per wave
  constexpr int TILE = (BM + BN) * 64; // elems per buffer
  __shared__ bf16 sm[2 * TILE];

  const int t = threadIdx.x;
  const int wid = t >> 6, lane = t & 63;
  const int quad = lane >> 4, l16 = lane & 15;
  const int wr = wid >> 2, wc = wid & 3;
  const int wm = wr * (BM / 2), wn = wc * (BN / 4);
  const long m0 = (long)blockIdx.x * BM;
  const long n0 = (long)blockIdx.y * BN;

  const bf16* src[L];
  int dst[L];
#pragma unroll
  for (int i = 0; i < L; i++) {
    const int ci = i * 512 + t;
    if (i * 512 < CA) {
      const int row = ci >> 3;
      const int col = ((ci & 7) ^ (row & 7)) * 8;
      src[i] = A + (m0 + row) * K + col;
    } else {
      const int cj = ci - CA;
      const int row = cj >> 3;
      const int col = ((cj & 7) ^ (row & 7)) * 8;
      src[i] = BT + (n0 + row) * K + col;
    }
    dst[i] = ci * 8;
  }

  f32x4 acc[2 * MRH][NR] = {};
  const int NT = K >> 6;

#pragma unroll
  for (int i = 0; i < L; i++) async16(src[i], sm + dst[i]);

  for (int tau = 0; tau < NT; tau++) {
    const int cur = tau & 1;
    const bf16* Asb = sm + cur * TILE;
    const bf16* Bsb = Asb + BM * 64;
    bf16* nb = sm + (cur ^ 1) * TILE;
    const bool pf = (tau + 1 < NT);
    const long ko = (long)(tau + 1) * 64;

    if (pf) {
#pragma unroll
      for (int i = 0; i < B0; i++) async16(src[i] + ko, nb + dst[i]);
      asm volatile("s_waitcnt vmcnt(%0)" ::"n"(B0) : "memory");
    } else {
      asm volatile("s_waitcnt vmcnt(0)" ::: "memory");
    }
    __builtin_amdgcn_s_barrier();

    short8 bfr[NR], af[MRH];
    // ---- P1: kc=0, m-half 0 ----
#pragma unroll
    for (int ni = 0; ni < NR; ni++)
      bfr[ni] = *(const short8*)(Bsb + (wn + ni * 16 + l16) * 64 + ((quad ^ (l16 & 7)) << 3));
#pragma unroll
    for (int mi = 0; mi < MRH; mi++)
      af[mi] = *(const short8*)(Asb + (wm + mi * 16 + l16) * 64 + ((quad ^ (l16 & 7)) << 3));
    if (pf) {
#pragma unroll
      for (int i = B0; i < B0 + B1; i++) async16(src[i] + ko, nb + dst[i]);
    }
    __builtin_amdgcn_s_setprio(1);
#pragma unroll
    for (int mi = 0; mi < MRH; mi++)
#pragma unroll
      for (int ni = 0; ni < NR; ni++)
        acc[mi][ni] = mfma_bf16(af[mi], bfr[ni], acc[mi][ni]);
    __builtin_amdgcn_s_setprio(0);
    __builtin_amdgcn_s_barrier();

    // ---- P2: kc=0, m-half 1 ----
#pragma unroll
    for (int mi = 0; mi < MRH; mi++)
      af[mi] = *(const short8*)(Asb + (wm + (MRH + mi) * 16 + l16) * 64 + ((quad ^ (l16 & 7)) << 3));
    if (pf) {
#pragma unroll
      for (int i = B0 + B1; i < B0 + B1 + B2; i++) async16(src[i] + ko, nb + dst[i]);
    }
    __builtin_amdgcn_s_setprio(1);
#pragma unroll
    for (int mi = 0; mi < MRH; mi++)
#pragma unroll
      for (int ni = 0; ni < NR; ni++)
        acc[MRH + mi][ni] = mfma_bf16(af[mi], bfr[ni], acc[MRH + mi][ni]);
    __builtin_amdgcn_s_setprio(0);
    __builtin_amdgcn_s_barrier();

    // ---- P3: kc=1, m-half 0 ----
#pragma unroll
    for (int ni = 0; ni < NR; ni++)
      bfr[ni] = *(const short8*)(Bsb + (wn + ni * 16 + l16) * 64 + (((4 + quad) ^ (l16 & 7)) << 3));
#pragma unroll
    for (int mi = 0; mi < MRH; mi++)
      af[mi] = *(const short8*)(Asb + (wm + mi * 16 + l16) * 64 + (((4 + quad) ^ (l16 & 7)) << 3));
    if (pf) {
#pragma unroll
      for (int i = B0 + B1 + B2; i < L; i++) async16(src[i] + ko, nb + dst[i]);
    }
    __builtin_amdgcn_s_setprio(1);
#pragma unroll
    for (int mi = 0; mi < MRH; mi++)
#pragma unroll
      for (int ni = 0; ni < NR; ni++)
        acc[mi][ni] = mfma_bf16(af[mi], bfr[ni], acc[mi][ni]);
    __builtin_amdgcn_s_setprio(0);
    __builtin_amdgcn_s_barrier();

    // ---- P4: kc=1, m-half 1 ----
#pragma unroll
    for (int mi = 0; mi < MRH; mi++)
      af[mi] = *(const short8*)(Asb + (wm + (MRH + mi) * 16 + l16) * 64 + (((4 + quad) ^ (l16 & 7)) << 3));
    __builtin_amdgcn_s_setprio(1);
#pragma unroll
    for (int mi = 0; mi < MRH; mi++)
#pragma unroll
      for (int ni = 0; ni < NR; ni++)
        acc[MRH + mi][ni] = mfma_bf16(af[mi], bfr[ni], acc[MRH + mi][ni]);
    __builtin_amdgcn_s_setprio(0);
    asm volatile("s_waitcnt lgkmcnt(0)" ::: "memory");
    __builtin_amdgcn_s_barrier();
  }

#pragma unroll
  for (int mi = 0; mi < 2 * MRH; mi++)
#pragma unroll
    for (int ni = 0; ni < NR; ni++)
#pragma unroll
      for (int r = 0; r < 4; r++) {
        long row = m0 + wm + mi * 16 + quad * 4 + r;
        long col = n0 + wn + ni * 16 + l16;
        store_c(C + row * ldc + col, acc[mi][ni][r]);
      }
}

// ---------------- QKV post: rmsnorm + rope + cache writes ----------------
__global__ __launch_bounds__(256) void qkv_post(
    const bf16* __restrict__ qkv, const float* __restrict__ qw,
    const float* __restrict__ kw, const float* __restrict__ rcos,
    const float* __restrict__ rsin, bf16* __restrict__ Q, bf16* __restrict__ Kb,
    float* __restrict__ kcache, float* __restrict__ vcache) {
  const int bs = blockIdx.x;
  const int b = bs >> 11;
  const int s = bs & 2047;
  const int t = threadIdx.x, wid = t >> 6, lane = t & 63;
  const int d0 = lane * 2;
  const bf16* row = qkv + (long)bs * QKVN;
  float cs = 0.f, sn = 0.f;
  if (lane < 16) {
    cs = rcos[s * 16 + lane];
    sn = rsin[s * 16 + lane];
  }
  for (int seg = wid; seg < 24; seg += 4) {
    if (seg < 16) {
      int h = seg;
      __hip_bfloat162 xr = *(const __hip_bfloat162*)(row + h * 256 + d0);
      float x0 = __bfloat162float(xr.x), x1 = __bfloat162float(xr.y);
      float ss = x0 * x0 + x1 * x1;
      for (int o = 32; o; o >>= 1) ss += __shfl_xor(ss, o, 64);
      float rn = rsqrtf(ss * (1.0f / 128.0f) + EPS_F);
      float y0 = x0 * rn * (1.0f + qw[d0]);
      float y1 = x1 * rn * (1.0f + qw[d0 + 1]);
      if (lane < 16) {
        float t0 = y0 * cs - y1 * sn;
        y1 = y1 * cs + y0 * sn;
        y0 = t0;
      }
      y0 *= QSCALE;  // fold softmax scale * log2(e) into Q
      y1 *= QSCALE;
      __hip_bfloat162 o2;
      o2.x = __float2bfloat16(y0); o2.y = __float2bfloat16(y1);
      *(__hip_bfloat162*)(Q + ((long)(b * NHEADS + h) * S_LEN + s) * HDIM + d0) = o2;
    } else if (seg < 20) {
      int j = seg - 16;
      __hip_bfloat162 xr = *(const __hip_bfloat162*)(row + 4096 + j * 128 + d0);
      float x0 = __bfloat162float(xr.x), x1 = __bfloat162float(xr.y);
      float ss = x0 * x0 + x1 * x1;
      for (int o = 32; o; o >>= 1) ss += __shfl_xor(ss, o, 64);
      float rn = rsqrtf(ss * (1.0f / 128.0f) + EPS_F);
      float y0 = x0 * rn * (1.0f + kw[d0]);
      float y1 = x1 * rn * (1.0f + kw[d0 + 1]);
      if (lane < 16) {
        float t0 = y0 * cs - y1 * sn;
        y1 = y1 * cs + y0 * sn;
        y0 = t0;
      }
      long idx = ((long)(b * NKVH + j) * S_LEN + s) * HDIM + d0;
      __hip_bfloat162 o2;
      o2.x = __float2bfloat16(y0); o2.y = __float2bfloat16(y1);
      *(__hip_bfloat162*)(Kb + idx) = o2;
      float2 f2; f2.x = y0; f2.y = y1;
      *(float2*)(kcache + idx) = f2;
    } else {
      int j = seg - 20;
      __hip_bfloat162 xr = *(const __hip_bfloat162*)(row + 4608 + j * 128 + d0);
      float2 f2;
      f2.x = __bfloat162float(xr.x); f2.y = __bfloat162float(xr.y);
      *(float2*)(vcache + ((long)(b * NKVH + j) * S_LEN + s) * HDIM + d0) = f2;
    }
  }
}

// ---------------- flash attention (causal, GQA) + fused sigmoid gate ----------------
// Balanced split-K schedule (fixed-max softmax -> partials combine by addition).
// 512 threads = 8 waves = 4 heads x 2 q-halves sharing ONE staged K/V tile.
// NEW: KT=128 double-tiles -> HALF the barrier/drain events, 2x MFMA per event
// (128 MFMA/wave/tile). K/V both double-buffered with counted vmcnt; P written
// and consumed in 32-key chunks (32x32 slab/wave) so P-LDS shrinks to 16 KB.
// Split-K in dbl units: T(qt)=(qt>>1)+1; half=0: dbl [0,8) (keys [0,1024), slot0);
// half=1: qt_hi dbl [8,T_hi) + qt_lo full -> same key ranges as before, combine
// kernel unchanged. Odd diagonal boundaries: global causal mask on last dbl-tile
// (masked keys -> exp2 -> exactly 0 -> bit-identical sums).
// LDS: Ks 2x32K + VTs 2x32K + Ps 16K = 144 KB -> 1 block/CU.
__global__ __launch_bounds__(512, 2) void flash_attn(
    const bf16* __restrict__ Q, const bf16* __restrict__ Kb,
    const bf16* __restrict__ VT, const bf16* __restrict__ qkv,
    bf16* __restrict__ Aout, float* __restrict__ Opart,
    float* __restrict__ lpart) {
  __shared__ bf16 Ks[2][KT2 * 128];  // [key_row][chunk16^(row&15)] dbuf, 32 KB each
  __shared__ bf16 VTs[2][128 * KT2]; // [d_row][chunk16^(row&15)] dbuf, 32 KB each
  __shared__ bf16 Ps[8 * 32 * 32];   // per-wave 32x32 chunk slab, chunk^(row&3)
  const int bid = blockIdx.x;
  const int group = bid & 7;       // (b,kvh): XCD-pin; 1 MB K/V window
  const int b = group >> 2;
  const int kvh = group & 3;
  const int j = bid >> 3;          // [0,32)
  const int p = j >> 1;            // [0,16)
  const int half = j & 1;
  const int t = threadIdx.x, w = t >> 6, lane = t & 63;
  const int quad = lane >> 4, l16 = lane & 15;
  const int hh = w & 3, qseg = w >> 2;
  const int h = kvh * 4 + hh;

  const bf16* Kbase = Kb + (long)(b * NKVH + kvh) * S_LEN * HDIM;
  const bf16* VTbase = VT + (long)(b * NKVH + kvh) * HDIM * S_LEN;
  bf16* Pw = Ps + w * (32 * 32);

  const int nseg = 1 + half;
  int qt = 16 + p;
  int kt0 = half ? KSPLIT_D : 0;
  int kt1 = half ? ((qt >> 1) + 1) : KSPLIT_D;

  for (int seg = 0; seg < nseg; seg++) {
    if (seg == 1) { qt = 15 - p; kt0 = 0; kt1 = (qt >> 1) + 1; }
    const int qm0 = qt * 64;

    const bf16* Qb = Q + ((long)(b * NHEADS + h) * S_LEN + qm0 + qseg * 32) * HDIM;
    short8 qf[2][4];
#pragma unroll
    for (int mi = 0; mi < 2; mi++)
#pragma unroll
      for (int kc = 0; kc < 4; kc++)
        qf[mi][kc] = *(const short8*)(Qb + (mi * 16 + l16) * HDIM + kc * 32 + quad * 8);

    f32x4 oacc[2][8] = {};
    float lrun[2][4] = {};  // per-lane partial row sums

    // prologue: stage K(kt0) then V(kt0) into buffer 0 (4+4 loads/thread)
#pragma unroll
    for (int i = 0; i < 4; i++) {
      int ci = i * 512 + t;
      int kr = ci >> 4;
      async16(Kbase + (long)(kt0 * KT2 + kr) * HDIM + (((ci & 15) ^ (kr & 15)) << 3),
              Ks[0] + ci * 8);
    }
#pragma unroll
    for (int i = 0; i < 4; i++) {
      int ci = i * 512 + t;
      int vr = ci >> 4;
      async16(VTbase + (long)vr * S_LEN + kt0 * KT2 + (((ci & 15) ^ (vr & 15)) << 3),
              VTs[0] + ci * 8);
    }

    for (int kt = kt0; kt < kt1; kt++) {
      const int cur = (kt - kt0) & 1;
      const bool pf = (kt + 1 < kt1);
      const int kn1 = (kt + 1) * KT2;

      if (pf) {
        // issue next dbl-tile's K and V into the other buffer (8 loads/thread)
#pragma unroll
        for (int i = 0; i < 4; i++) {
          int ci = i * 512 + t;
          int kr = ci >> 4;
          async16(Kbase + (long)(kn1 + kr) * HDIM + (((ci & 15) ^ (kr & 15)) << 3),
                  Ks[cur ^ 1] + ci * 8);
        }
#pragma unroll
        for (int i = 0; i < 4; i++) {
          int ci = i * 512 + t;
          int vr = ci >> 4;
          async16(VTbase + (long)vr * S_LEN + kn1 + (((ci & 15) ^ (vr & 15)) << 3),
                  VTs[cur ^ 1] + ci * 8);
        }
        asm volatile("s_waitcnt vmcnt(8)" ::: "memory");  // K(kt),V(kt) landed
      } else {
        asm volatile("s_waitcnt vmcnt(0)" ::: "memory");
      }
      barrier_f();  // all waves' K(kt)/V(kt) landed; safe to read buffers [cur]

      // S = Q @ K^T over 128 keys (swizzled reads: conflict-free)
      const bf16* Kcur = Ks[cur];
      f32x4 sacc[2][8] = {};
#pragma unroll
      for (int kq = 0; kq < 4; kq++) {
        short8 bfr[8];
#pragma unroll
        for (int ni = 0; ni < 8; ni++)
          bfr[ni] = *(const short8*)(Kcur + (ni * 16 + l16) * 128 + (((kq * 4 + quad) ^ l16) << 3));
        __builtin_amdgcn_s_setprio(1);
#pragma unroll
        for (int ni = 0; ni < 8; ni++)
#pragma unroll
          for (int mi = 0; mi < 2; mi++)
            sacc[mi][ni] = mfma_bf16(qf[mi][kq], bfr[ni], sacc[mi][ni]);
        __builtin_amdgcn_s_setprio(0);
      }

      // fixed-max softmax: p = exp2(s - 17); per-lane partial row sums.
      // Causal mask (global index compare) on the last dbl-tile of this q-tile.
      const bool lastk = (kt == (qt >> 1));
      const int kb = kt * KT2;
#pragma unroll
      for (int mi = 0; mi < 2; mi++)
#pragma unroll
        for (int r = 0; r < 4; r++) {
          const int qg = qm0 + qseg * 32 + mi * 16 + quad * 4 + r;  // global query row
          if (lastk) {
#pragma unroll
            for (int ni = 0; ni < 8; ni++)
              if (kb + ni * 16 + l16 > qg) sacc[mi][ni][r] = NEG_INF;
          }
          float rsum = lrun[mi][r];
#pragma unroll
          for (int ni = 0; ni < 8; ni++) {
            float pv = exp2f(sacc[mi][ni][r] - FIXED_M);
            sacc[mi][ni][r] = pv;
            rsum += pv;
          }
          lrun[mi][r] = rsum;
        }

      // O += P @ V, chunked: per 32-key slice kc, write P chunk to own slab then MFMA.
      // Same-wave LDS RAW is ordered -> no barrier/waitcnt needed on own slab.
      const bf16* Vcur = VTs[cur];
#pragma unroll
      for (int kc = 0; kc < 4; kc++) {
#pragma unroll
        for (int mi = 0; mi < 2; mi++)
#pragma unroll
          for (int jj = 0; jj < 2; jj++)
#pragma unroll
            for (int r = 0; r < 4; r++) {
              const int row = mi * 16 + quad * 4 + r;
              Pw[row * 32 + (((jj * 2 + (l16 >> 3)) ^ (row & 3)) << 3) + (l16 & 7)] =
                  __float2bfloat16(sacc[mi][kc * 2 + jj][r]);
            }
        short8 pfr[2];
#pragma unroll
        for (int mi = 0; mi < 2; mi++) {
          const int row = mi * 16 + l16;
          pfr[mi] = *(const short8*)(Pw + row * 32 + ((quad ^ (row & 3)) << 3));
        }
#pragma unroll
        for (int ni = 0; ni < 8; ni++) {
          short8 vf = *(const short8*)(Vcur + (ni * 16 + l16) * 128 +
                                       (((kc * 4 + quad) ^ l16) << 3));
          __builtin_amdgcn_s_setprio(1);
#pragma unroll
          for (int mi = 0; mi < 2; mi++)
            oacc[mi][ni] = mfma_bf16(pfr[mi], vf, oacc[mi][ni]);
          __builtin_amdgcn_s_setprio(0);
        }
      }

      barrier_f();  // all waves done reading [cur]; next iter may overwrite it
    }

    if (seg == 0) {
      // partial epilogue: un-normalized O (f32) + row sums to workspace slot 'half'
      float* Ob = Opart + (((long)half * 2 + b) * NHEADS + h) * (1024L * 128);
      float* lb = lpart + (((long)half * 2 + b) * NHEADS + h) * 1024L;
#pragma unroll
      for (int mi = 0; mi < 2; mi++)
#pragma unroll
        for (int r = 0; r < 4; r++) {
          float s = lrun[mi][r];
#pragma unroll
          for (int o = 1; o < 16; o <<= 1) s += __shfl_xor(s, o, 64);
          const long r10 = (long)qm0 - 1024 + qseg * 32 + mi * 16 + quad * 4 + r;
          if (l16 == 0) lb[r10] = s;
#pragma unroll
          for (int ni = 0; ni < 8; ni++)
            Ob[r10 * 128 + ni * 16 + l16] = oacc[mi][ni][r];
        }
    } else {
      // full epilogue: reduce row sums, repack O via own P slab (32-col chunks),
      // gate, coalesced store
      float inv[2][4];
#pragma unroll
      for (int mi = 0; mi < 2; mi++)
#pragma unroll
        for (int r = 0; r < 4; r++) {
          float s = lrun[mi][r];
#pragma unroll
          for (int o = 1; o < 16; o <<= 1) s += __shfl_xor(s, o, 64);
          inv[mi][r] = 1.0f / s;
        }

#pragma unroll
      for (int h2 = 0; h2 < 4; h2++) {  // 4 chunks of 32 output cols
        barrier_f();  // slab reuse across h2 iterations is wave-private; barrier not
                      // strictly needed but keeps waves phase-aligned cheaply
#pragma unroll
        for (int mi = 0; mi < 2; mi++)
#pragma unroll
          for (int jj = 0; jj < 2; jj++)
#pragma unroll
            for (int r = 0; r < 4; r++) {
              const int row = mi * 16 + quad * 4 + r;
              Pw[row * 32 + (((jj * 2 + (l16 >> 3)) ^ (row & 3)) << 3) + (l16 & 7)] =
                  __float2bfloat16(oacc[mi][h2 * 2 + jj][r] * inv[mi][r]);
            }
        // readback rows, apply sigmoid gate (8B loads), 8B coalesced stores
#pragma unroll
        for (int i = 0; i < 8; i++) {
          const int lrow = i * 4 + (lane >> 4);
          const int coff = (lane & 15) * 2;
          const int ch = coff >> 3;  // chunk 0..3
          const bf16* pp = Pw + lrow * 32 + (((ch ^ (lrow & 3))) << 3) + (coff & 7);
          short s0 = *(const short*)pp;
          short s1 = *(const short*)(pp + 1);
          const long srow = qm0 + qseg * 32 + lrow;
          const bf16* gp = qkv + ((long)b * S_LEN + srow) * QKVN + h * 256 + 128 + h2 * 32 + coff;
          short g0 = *(const short*)gp;
          short g1 = *(const short*)(gp + 1);
          short8 dummy;
          short2_t:;
          short res0 = f_to_bfbits(bfbits_to_f(s0) / (1.0f + __expf(-bfbits_to_f(g0))));
          short res1 = f_to_bfbits(bfbits_to_f(s1) / (1.0f + __expf(-bfbits_to_f(g1))));
          short* op = (short*)(Aout + ((long)b * S_LEN + srow) * 2048 + h * 128 + h2 * 32 + coff);
          op[0] = res0;
          op[1] = res1;
          (void)dummy;
        }
      }
    }
  }
}

// ---------------- combine split-K partials for q-rows 1024..2047 ----------------
// O = (O0 + O1) / (l0 + l1), then sigmoid gate, bf16 store to Aout.
__global__ __launch_bounds__(256) void combine_attn(
    const float* __restrict__ Opart, const float* __restrict__ lpart,
    const bf16* __restrict__ qkv, bf16* __restrict__ Aout) {
  const long tid = (long)blockIdx.x * 256 + threadIdx.x;  // [0, 524288)
  const int d0 = ((int)tid & 15) * 8;
  const long rh = tid >> 4;                               // [0, 32768): b*16384+h*1024+r
  const int r = (int)(rh & 1023);
  const int h = (int)((rh >> 10) & 15);
  const int b = (int)(rh >> 14);
  const float inv = 1.0f / (lpart[rh] + lpart[rh + 32768]);
  const float* O0 = Opart + rh * 128 + d0;
  const float* O1 = O0 + 4194304L;  // half-slot stride = 2*16*1024*128
  float4 a0 = *(const float4*)O0;
  float4 a1 = *(const float4*)(O0 + 4);
  float4 c0 = *(const float4*)O1;
  float4 c1 = *(const float4*)(O1 + 4);
  const long srow = 1024 + r;
  const bf16* gp = qkv + ((long)b * S_LEN + srow) * QKVN + h * 256 + 128 + d0;
  short8 g8 = *(const short8*)gp;
  float ov[8] = {a0.x + c0.x, a0.y + c0.y, a0.z + c0.z, a0.w + c0.w,
                 a1.x + c1.x, a1.y + c1.y, a1.z + c1.z, a1.w + c1.w};
  short8 res;
#pragma unroll
  for (int e = 0; e < 8; e++) {
    float gv = bfbits_to_f(g8[e]);
    res[e] = f_to_bfbits(ov[e] * inv / (1.0f + __expf(-gv)));
  }
  *(short8*)(Aout + ((long)b * S_LEN + srow) * 2048 + h * 128 + d0) = res;
}

extern "C" void kernel_launch(void* const* d_in, const int* in_sizes, int n_in,
                              void* d_out, int out_size, void* d_ws, size_t ws_size,
                              hipStream_t stream) {
  const float* hs = (const float*)d_in[0];
  const float* wq = (const float*)d_in[1];
  const float* wk = (const float*)d_in[2];
  const float* wv = (const float*)d_in[3];
  const float* wo = (const float*)d_in[4];
  const float* qnw = (const float*)d_in[5];
  const float* knw = (const float*)d_in[6];
  const float* rcos = (const float*)d_in[7];
  const float* rsin = (const float*)d_in[8];

  float* out = (float*)d_out;                 // (2,2048,2048)
  float* kcache = out + 8388608;              // (2,4,2048,128)
  float* vcache = out + 10485760;             // (2,4,2048,128)

  char* ws = (char*)d_ws;
  bf16* Xb    = (bf16*)(ws);                  // (4096,2048)
  bf16* WqkvT = (bf16*)(ws + 16777216L);      // (5120,2048)
  bf16* WoT   = (bf16*)(ws + 37748736L);      // (2048,2048)
  bf16* QKV   = (bf16*)(ws + 46137344L);      // (4096,5120)
  bf16* Qb    = (bf16*)(ws + 88080384L);      // (2,16,2048,128)
  bf16* Kbq   = (bf16*)(ws + 104857600L);     // (2,4,2048,128)
  bf16* VTb   = (bf16*)(ws + 109051904L);     // (2,4,128,2048)
  bf16* Aout  = (bf16*)(ws + 113246208L);     // (4096,2048)
  // split-K partials: reuse Xb/WqkvT region (dead after the QKV GEMM).
  // Opart [2][2][16][1024][128] f32 = 33,554,432 B; lpart = 262,144 B; end < WoT.
  float* Opart = (float*)(ws);
  float* lpart = (float*)(ws + 33554432L);

  // fused prep: cast hs->Xb + transpose wq/wk/wv->WqkvT + wo->WoT (one launch)
  prep_fused<<<22528, 256, 0, stream>>>(hs, wq, wk, wv, wo, Xb, WqkvT, WoT);

  // QKV GEMM: (4096x2048) x (5120x2048)^T -> 256x320 tiles, grid 16x16 = 256 blocks
  gemm_big<bf16, 256, 320, 3, 2, 2, 2><<<dim3(16, 16), 512, 0, stream>>>(Xb, WqkvT, QKV, 2048, 5120);

  qkv_post<<<4096, 256, 0, stream>>>(QKV, qnw, knw, rcos, rsin, Qb, Kbq, kcache, vcache);

  // V^T (per (b,kv): (2048,128) f32 -> (128,2048) bf16)
  transpose_cast<<<dim3(4, 64, 8), dim3(32, 8), 0, stream>>>(vcache, VTb, 2048, 128,
                                                             2048L * 128, 2048L * 128);

  flash_attn<<<256, 512, 0, stream>>>(Qb, Kbq, VTb, QKV, Aout, Opart, lpart);
  combine_attn<<<2048, 256, 0, stream>>>(Opart, lpart, QKV, Aout);

  // output GEMM: (4096x2048) x (2048x2048)^T -> 128x256 tiles, grid 32x8 = 256 blocks
  gemm_big<float, 128, 256, 2, 2, 1, 1><<<dim3(32, 8), 512, 0, stream>>>(Aout, WoT, out, 2048, 2048);
}

// Round 9
// 357.425 us; speedup vs baseline: 1.4172x; 1.4172x over previous
//
#include <hip/hip_runtime.h>
#include <hip/hip_bf16.h>

typedef __hip_bfloat16 bf16;
typedef short short8 __attribute__((ext_vector_type(8)));
typedef float f32x4 __attribute__((ext_vector_type(4)));

#define S_LEN 2048
#define NHEADS 16
#define NKVH 4
#define HDIM 128
#define QKVN 5120
#define EPS_F 1e-6f
#define NEG_INF -1e30f
// SCALE * log2(e): attention scores computed in base-2 domain
#define QSCALE 0.12751744f
// |score*log2e| <= sqrt(128)*sqrt(128)*SCALE*log2e = 16.33 -> fixed softmax max
#define FIXED_M 17.0f

#define KT 64
// split point (in K-tiles) for the balanced split-K schedule
#define KSPLIT 16

__device__ __forceinline__ void async16(const bf16* g, bf16* l) {
  __builtin_amdgcn_global_load_lds(
      (const __attribute__((address_space(1))) void*)g,
      (__attribute__((address_space(3))) void*)l, 16, 0, 0);
}

__device__ __forceinline__ f32x4 mfma_bf16(short8 a, short8 b, f32x4 c) {
  return __builtin_amdgcn_mfma_f32_16x16x32_bf16(a, b, c, 0, 0, 0);
}

__device__ __forceinline__ float bfbits_to_f(short s) {
  unsigned u = ((unsigned)(unsigned short)s) << 16;
  return __uint_as_float(u);
}
__device__ __forceinline__ short f_to_bfbits(float f) {
  __hip_bfloat16 h = __float2bfloat16(f);
  return *reinterpret_cast<short*>(&h);
}

__device__ __forceinline__ void store_c(float* p, float v) { *p = v; }
__device__ __forceinline__ void store_c(bf16* p, float v) { *p = __float2bfloat16(v); }

// barrier + compiler memory fence (keep LDS reads from sliding above the barrier)
__device__ __forceinline__ void barrier_f() {
  __builtin_amdgcn_s_barrier();
  asm volatile("" ::: "memory");
}

// ---------------- fused prep: f32->bf16 cast of hs + 4 transposes, ONE launch ----------
__device__ __forceinline__ void do_transpose(const float* __restrict__ in,
                                             bf16* __restrict__ out, int N,
                                             int bx, int by, int t) {
  __shared__ float tile[32][33];
  const int H = 2048;
  int n0 = bx * 32, h0 = by * 32;
  int tx = t & 31, ty = t >> 5;
#pragma unroll
  for (int i = 0; i < 4; i++)
    tile[ty + i * 8][tx] = in[(long)(h0 + ty + i * 8) * N + n0 + tx];
  __syncthreads();
#pragma unroll
  for (int i = 0; i < 4; i++)
    out[(long)(n0 + ty + i * 8) * H + h0 + tx] = __float2bfloat16(tile[tx][ty + i * 8]);
}

__global__ __launch_bounds__(256) void prep_fused(const float* __restrict__ hs,
                                                  const float* __restrict__ wq,
                                                  const float* __restrict__ wk,
                                                  const float* __restrict__ wv,
                                                  const float* __restrict__ wo,
                                                  bf16* __restrict__ Xb,
                                                  bf16* __restrict__ WqkvT,
                                                  bf16* __restrict__ WoT) {
  const int bid = blockIdx.x;
  const int t = threadIdx.x;
  if (bid < 8192) {
    do_transpose(wq, WqkvT, 4096, bid & 127, bid >> 7, t);
  } else if (bid < 9216) {
    int l = bid - 8192;
    do_transpose(wk, WqkvT + 4096L * 2048, 512, l & 15, l >> 4, t);
  } else if (bid < 10240) {
    int l = bid - 9216;
    do_transpose(wv, WqkvT + 4608L * 2048, 512, l & 15, l >> 4, t);
  } else if (bid < 14336) {
    int l = bid - 10240;
    do_transpose(wo, WoT, 2048, l & 63, l >> 6, t);
  } else {
    int i = ((bid - 14336) * 256 + t) * 4;
    float4 v = *(const float4*)(hs + i);
    __hip_bfloat162 p0, p1;
    p0.x = __float2bfloat16(v.x); p0.y = __float2bfloat16(v.y);
    p1.x = __float2bfloat16(v.z); p1.y = __float2bfloat16(v.w);
    *(__hip_bfloat162*)(Xb + i) = p0;
    *(__hip_bfloat162*)(Xb + i + 2) = p1;
  }
}

// ---------------- tiled transpose + cast: in (H,N) f32 -> out (N,H) bf16 ----------------
__global__ __launch_bounds__(256) void transpose_cast(const float* __restrict__ in,
                                                      bf16* __restrict__ out, int H, int N,
                                                      long inBS, long outBS) {
  __shared__ float tile[32][33];
  const float* ip = in + (long)blockIdx.z * inBS;
  bf16* op = out + (long)blockIdx.z * outBS;
  int n0 = blockIdx.x * 32, h0 = blockIdx.y * 32;
  int tx = threadIdx.x, ty = threadIdx.y;
#pragma unroll
  for (int i = 0; i < 4; i++)
    tile[ty + i * 8][tx] = ip[(long)(h0 + ty + i * 8) * N + n0 + tx];
  __syncthreads();
#pragma unroll
  for (int i = 0; i < 4; i++)
    op[(long)(n0 + ty + i * 8) * H + h0 + tx] = __float2bfloat16(tile[tx][ty + i * 8]);
}

// ---------------- big-tile bt-form bf16 GEMM with counted-vmcnt pipeline ----------------
// NEW: XCD-aware block swizzle (T1). Grid must be 256 blocks (divisible by 8).
// flat' = (flat%8)*32 + flat/8 gives each XCD a contiguous run of tiles sharing
// B-panels -> panel stays in one XCD L2 instead of being fetched into all 8.
// Bijective remap of tile assignment only -> results bit-identical.
template <typename CT, int BM, int BN, int B0, int B1, int B2, int B3>
__global__ __launch_bounds__(512, 2) void gemm_big(const bf16* __restrict__ A,
                                                   const bf16* __restrict__ BT,
                                                   CT* __restrict__ C, int K, int ldc) {
  constexpr int L = (BM + BN) / 64;    // global_load_lds per thread per K-tile
  constexpr int CA = BM * 8;           // A-chunks per tile (multiple of 512)
  constexpr int MRH = BM / 64;         // m-frags per half-phase
  constexpr int NR = BN / 64;          // n-frags per wave
  constexpr int TILE = (BM + BN) * 64; // elems per buffer
  __shared__ bf16 sm[2 * TILE];

  const int t = threadIdx.x;
  const int wid = t >> 6, lane = t & 63;
  const int quad = lane >> 4, l16 = lane & 15;
  const int wr = wid >> 2, wc = wid & 3;
  const int wm = wr * (BM / 2), wn = wc * (BN / 4);

  // XCD swizzle: nwg = gridDim.x*gridDim.y (must be %8==0)
  const int nwg = gridDim.x * gridDim.y;
  const int flat = blockIdx.y * gridDim.x + blockIdx.x;
  const int swz = (flat & 7) * (nwg >> 3) + (flat >> 3);
  const int bx = swz % gridDim.x;
  const int by = swz / gridDim.x;
  const long m0 = (long)bx * BM;
  const long n0 = (long)by * BN;

  const bf16* src[L];
  int dst[L];
#pragma unroll
  for (int i = 0; i < L; i++) {
    const int ci = i * 512 + t;
    if (i * 512 < CA) {
      const int row = ci >> 3;
      const int col = ((ci & 7) ^ (row & 7)) * 8;
      src[i] = A + (m0 + row) * K + col;
    } else {
      const int cj = ci - CA;
      const int row = cj >> 3;
      const int col = ((cj & 7) ^ (row & 7)) * 8;
      src[i] = BT + (n0 + row) * K + col;
    }
    dst[i] = ci * 8;
  }

  f32x4 acc[2 * MRH][NR] = {};
  const int NT = K >> 6;

#pragma unroll
  for (int i = 0; i < L; i++) async16(src[i], sm + dst[i]);

  for (int tau = 0; tau < NT; tau++) {
    const int cur = tau & 1;
    const bf16* Asb = sm + cur * TILE;
    const bf16* Bsb = Asb + BM * 64;
    bf16* nb = sm + (cur ^ 1) * TILE;
    const bool pf = (tau + 1 < NT);
    const long ko = (long)(tau + 1) * 64;

    if (pf) {
#pragma unroll
      for (int i = 0; i < B0; i++) async16(src[i] + ko, nb + dst[i]);
      asm volatile("s_waitcnt vmcnt(%0)" ::"n"(B0) : "memory");
    } else {
      asm volatile("s_waitcnt vmcnt(0)" ::: "memory");
    }
    __builtin_amdgcn_s_barrier();

    short8 bfr[NR], af[MRH];
    // ---- P1: kc=0, m-half 0 ----
#pragma unroll
    for (int ni = 0; ni < NR; ni++)
      bfr[ni] = *(const short8*)(Bsb + (wn + ni * 16 + l16) * 64 + ((quad ^ (l16 & 7)) << 3));
#pragma unroll
    for (int mi = 0; mi < MRH; mi++)
      af[mi] = *(const short8*)(Asb + (wm + mi * 16 + l16) * 64 + ((quad ^ (l16 & 7)) << 3));
    if (pf) {
#pragma unroll
      for (int i = B0; i < B0 + B1; i++) async16(src[i] + ko, nb + dst[i]);
    }
    __builtin_amdgcn_s_setprio(1);
#pragma unroll
    for (int mi = 0; mi < MRH; mi++)
#pragma unroll
      for (int ni = 0; ni < NR; ni++)
        acc[mi][ni] = mfma_bf16(af[mi], bfr[ni], acc[mi][ni]);
    __builtin_amdgcn_s_setprio(0);
    __builtin_amdgcn_s_barrier();

    // ---- P2: kc=0, m-half 1 ----
#pragma unroll
    for (int mi = 0; mi < MRH; mi++)
      af[mi] = *(const short8*)(Asb + (wm + (MRH + mi) * 16 + l16) * 64 + ((quad ^ (l16 & 7)) << 3));
    if (pf) {
#pragma unroll
      for (int i = B0 + B1; i < B0 + B1 + B2; i++) async16(src[i] + ko, nb + dst[i]);
    }
    __builtin_amdgcn_s_setprio(1);
#pragma unroll
    for (int mi = 0; mi < MRH; mi++)
#pragma unroll
      for (int ni = 0; ni < NR; ni++)
        acc[MRH + mi][ni] = mfma_bf16(af[mi], bfr[ni], acc[MRH + mi][ni]);
    __builtin_amdgcn_s_setprio(0);
    __builtin_amdgcn_s_barrier();

    // ---- P3: kc=1, m-half 0 ----
#pragma unroll
    for (int ni = 0; ni < NR; ni++)
      bfr[ni] = *(const short8*)(Bsb + (wn + ni * 16 + l16) * 64 + (((4 + quad) ^ (l16 & 7)) << 3));
#pragma unroll
    for (int mi = 0; mi < MRH; mi++)
      af[mi] = *(const short8*)(Asb + (wm + mi * 16 + l16) * 64 + (((4 + quad) ^ (l16 & 7)) << 3));
    if (pf) {
#pragma unroll
      for (int i = B0 + B1 + B2; i < L; i++) async16(src[i] + ko, nb + dst[i]);
    }
    __builtin_amdgcn_s_setprio(1);
#pragma unroll
    for (int mi = 0; mi < MRH; mi++)
#pragma unroll
      for (int ni = 0; ni < NR; ni++)
        acc[mi][ni] = mfma_bf16(af[mi], bfr[ni], acc[mi][ni]);
    __builtin_amdgcn_s_setprio(0);
    __builtin_amdgcn_s_barrier();

    // ---- P4: kc=1, m-half 1 ----
#pragma unroll
    for (int mi = 0; mi < MRH; mi++)
      af[mi] = *(const short8*)(Asb + (wm + (MRH + mi) * 16 + l16) * 64 + (((4 + quad) ^ (l16 & 7)) << 3));
    __builtin_amdgcn_s_setprio(1);
#pragma unroll
    for (int mi = 0; mi < MRH; mi++)
#pragma unroll
      for (int ni = 0; ni < NR; ni++)
        acc[MRH + mi][ni] = mfma_bf16(af[mi], bfr[ni], acc[MRH + mi][ni]);
    __builtin_amdgcn_s_setprio(0);
    asm volatile("s_waitcnt lgkmcnt(0)" ::: "memory");
    __builtin_amdgcn_s_barrier();
  }

#pragma unroll
  for (int mi = 0; mi < 2 * MRH; mi++)
#pragma unroll
    for (int ni = 0; ni < NR; ni++)
#pragma unroll
      for (int r = 0; r < 4; r++) {
        long row = m0 + wm + mi * 16 + quad * 4 + r;
        long col = n0 + wn + ni * 16 + l16;
        store_c(C + row * ldc + col, acc[mi][ni][r]);
      }
}

// ---------------- QKV post: rmsnorm + rope + cache writes ----------------
__global__ __launch_bounds__(256) void qkv_post(
    const bf16* __restrict__ qkv, const float* __restrict__ qw,
    const float* __restrict__ kw, const float* __restrict__ rcos,
    const float* __restrict__ rsin, bf16* __restrict__ Q, bf16* __restrict__ Kb,
    float* __restrict__ kcache, float* __restrict__ vcache) {
  const int bs = blockIdx.x;
  const int b = bs >> 11;
  const int s = bs & 2047;
  const int t = threadIdx.x, wid = t >> 6, lane = t & 63;
  const int d0 = lane * 2;
  const bf16* row = qkv + (long)bs * QKVN;
  float cs = 0.f, sn = 0.f;
  if (lane < 16) {
    cs = rcos[s * 16 + lane];
    sn = rsin[s * 16 + lane];
  }
  for (int seg = wid; seg < 24; seg += 4) {
    if (seg < 16) {
      int h = seg;
      __hip_bfloat162 xr = *(const __hip_bfloat162*)(row + h * 256 + d0);
      float x0 = __bfloat162float(xr.x), x1 = __bfloat162float(xr.y);
      float ss = x0 * x0 + x1 * x1;
      for (int o = 32; o; o >>= 1) ss += __shfl_xor(ss, o, 64);
      float rn = rsqrtf(ss * (1.0f / 128.0f) + EPS_F);
      float y0 = x0 * rn * (1.0f + qw[d0]);
      float y1 = x1 * rn * (1.0f + qw[d0 + 1]);
      if (lane < 16) {
        float t0 = y0 * cs - y1 * sn;
        y1 = y1 * cs + y0 * sn;
        y0 = t0;
      }
      y0 *= QSCALE;  // fold softmax scale * log2(e) into Q
      y1 *= QSCALE;
      __hip_bfloat162 o2;
      o2.x = __float2bfloat16(y0); o2.y = __float2bfloat16(y1);
      *(__hip_bfloat162*)(Q + ((long)(b * NHEADS + h) * S_LEN + s) * HDIM + d0) = o2;
    } else if (seg < 20) {
      int j = seg - 16;
      __hip_bfloat162 xr = *(const __hip_bfloat162*)(row + 4096 + j * 128 + d0);
      float x0 = __bfloat162float(xr.x), x1 = __bfloat162float(xr.y);
      float ss = x0 * x0 + x1 * x1;
      for (int o = 32; o; o >>= 1) ss += __shfl_xor(ss, o, 64);
      float rn = rsqrtf(ss * (1.0f / 128.0f) + EPS_F);
      float y0 = x0 * rn * (1.0f + kw[d0]);
      float y1 = x1 * rn * (1.0f + kw[d0 + 1]);
      if (lane < 16) {
        float t0 = y0 * cs - y1 * sn;
        y1 = y1 * cs + y0 * sn;
        y0 = t0;
      }
      long idx = ((long)(b * NKVH + j) * S_LEN + s) * HDIM + d0;
      __hip_bfloat162 o2;
      o2.x = __float2bfloat16(y0); o2.y = __float2bfloat16(y1);
      *(__hip_bfloat162*)(Kb + idx) = o2;
      float2 f2; f2.x = y0; f2.y = y1;
      *(float2*)(kcache + idx) = f2;
    } else {
      int j = seg - 20;
      __hip_bfloat162 xr = *(const __hip_bfloat162*)(row + 4608 + j * 128 + d0);
      float2 f2;
      f2.x = __bfloat162float(xr.x); f2.y = __bfloat162float(xr.y);
      *(float2*)(vcache + ((long)(b * NKVH + j) * S_LEN + s) * HDIM + d0) = f2;
    }
  }
}

// ---------------- flash attention (causal, GQA) + fused sigmoid gate ----------------
// Round-7 version (verified 82 µs, 0 bank conflicts): 512 threads = 8 waves =
// 4 heads x 2 q-halves sharing ONE staged K/V tile; K/V double-buffer with
// counted vmcnt; setprio around MFMA clusters.
// (Round-8's KT=128 rewrite spilled registers -> 9x HBM traffic; reverted.)
// LDS: Ks 2x16K + VTs 2x16K + Ps 8x4K = 96 KB -> 1 block/CU.
__global__ __launch_bounds__(512, 2) void flash_attn(
    const bf16* __restrict__ Q, const bf16* __restrict__ Kb,
    const bf16* __restrict__ VT, const bf16* __restrict__ qkv,
    bf16* __restrict__ Aout, float* __restrict__ Opart,
    float* __restrict__ lpart) {
  __shared__ bf16 Ks[2][KT * 128];  // [key_row][chunk^(row&15)] 16B chunks, dbuf
  __shared__ bf16 VTs[2][128 * KT]; // [d_row][chunk^(row&7)], dbuf
  __shared__ bf16 Ps[8 * 32 * 64];  // per-wave 32x64, chunk^(row&7) swizzle
  const int bid = blockIdx.x;
  const int group = bid & 7;       // (b,kvh): XCD-pin; 1 MB K/V window
  const int b = group >> 2;
  const int kvh = group & 3;
  const int j = bid >> 3;          // [0,32)
  const int p = j >> 1;            // [0,16)
  const int half = j & 1;
  const int t = threadIdx.x, w = t >> 6, lane = t & 63;
  const int quad = lane >> 4, l16 = lane & 15;
  const int hh = w & 3, qseg = w >> 2;
  const int h = kvh * 4 + hh;

  const bf16* Kbase = Kb + (long)(b * NKVH + kvh) * S_LEN * HDIM;
  const bf16* VTbase = VT + (long)(b * NKVH + kvh) * HDIM * S_LEN;
  bf16* Pw = Ps + w * (32 * 64);

  const int nseg = 1 + half;
  int qt = 16 + p;
  int kt0 = half ? KSPLIT : 0;
  int kt1 = half ? (qt + 1) : KSPLIT;

  for (int seg = 0; seg < nseg; seg++) {
    if (seg == 1) { qt = 15 - p; kt0 = 0; kt1 = qt + 1; }
    const int qm0 = qt * 64;

    const bf16* Qb = Q + ((long)(b * NHEADS + h) * S_LEN + qm0 + qseg * 32) * HDIM;
    short8 qf[2][4];
#pragma unroll
    for (int mi = 0; mi < 2; mi++)
#pragma unroll
      for (int kc = 0; kc < 4; kc++)
        qf[mi][kc] = *(const short8*)(Qb + (mi * 16 + l16) * HDIM + kc * 32 + quad * 8);

    f32x4 oacc[2][8] = {};
    float lrun[2][4] = {};  // per-lane partial row sums

    // prologue: stage K(kt0) then V(kt0) into buffer 0 (2+2 loads/thread)
#pragma unroll
    for (int i = 0; i < 2; i++) {
      int ci = i * 512 + t;
      int kr = ci >> 4;
      async16(Kbase + (long)(kt0 * KT + kr) * HDIM + (((ci & 15) ^ (kr & 15)) << 3),
              Ks[0] + ci * 8);
    }
#pragma unroll
    for (int i = 0; i < 2; i++) {
      int ci = i * 512 + t;
      int vr = ci >> 3;
      async16(VTbase + (long)vr * S_LEN + kt0 * KT + (((ci & 7) ^ (vr & 7)) << 3),
              VTs[0] + ci * 8);
    }

    for (int kt = kt0; kt < kt1; kt++) {
      const int cur = (kt - kt0) & 1;
      const bool pf = (kt + 1 < kt1);
      const int kn1 = (kt + 1) * KT;

      if (pf) {
        // issue next tile's K and V into the other buffer (4 loads/thread)
#pragma unroll
        for (int i = 0; i < 2; i++) {
          int ci = i * 512 + t;
          int kr = ci >> 4;
          async16(Kbase + (long)(kn1 + kr) * HDIM + (((ci & 15) ^ (kr & 15)) << 3),
                  Ks[cur ^ 1] + ci * 8);
        }
#pragma unroll
        for (int i = 0; i < 2; i++) {
          int ci = i * 512 + t;
          int vr = ci >> 3;
          async16(VTbase + (long)vr * S_LEN + kn1 + (((ci & 7) ^ (vr & 7)) << 3),
                  VTs[cur ^ 1] + ci * 8);
        }
        asm volatile("s_waitcnt vmcnt(4)" ::: "memory");  // K(kt),V(kt) landed
      } else {
        asm volatile("s_waitcnt vmcnt(0)" ::: "memory");
      }
      barrier_f();  // all waves' K(kt)/V(kt) landed; safe to read buffers [cur]

      // S = Q @ K^T (swizzled reads: conflict-free)
      const bf16* Kcur = Ks[cur];
      f32x4 sacc[2][4] = {};
#pragma unroll
      for (int kc = 0; kc < 4; kc++) {
        short8 bfr[4];
#pragma unroll
        for (int ni = 0; ni < 4; ni++)
          bfr[ni] = *(const short8*)(Kcur + (ni * 16 + l16) * 128 + (((kc * 4 + quad) ^ l16) << 3));
        __builtin_amdgcn_s_setprio(1);
#pragma unroll
        for (int ni = 0; ni < 4; ni++)
#pragma unroll
          for (int mi = 0; mi < 2; mi++)
            sacc[mi][ni] = mfma_bf16(qf[mi][kc], bfr[ni], sacc[mi][ni]);
        __builtin_amdgcn_s_setprio(0);
      }

      // fixed-max softmax: p = exp2(s - 17); per-lane partial row sums
      const bool diag = (kt == qt);
#pragma unroll
      for (int mi = 0; mi < 2; mi++)
#pragma unroll
        for (int r = 0; r < 4; r++) {
          const int ql = qseg * 32 + mi * 16 + quad * 4 + r;  // local query in [0,64)
          if (diag) {
#pragma unroll
            for (int ni = 0; ni < 4; ni++)
              if (ni * 16 + l16 > ql) sacc[mi][ni][r] = NEG_INF;
          }
          float rsum = lrun[mi][r];
#pragma unroll
          for (int ni = 0; ni < 4; ni++) {
            float pv = exp2f(sacc[mi][ni][r] - FIXED_M);
            sacc[mi][ni][r] = pv;
            rsum += pv;
          }
          lrun[mi][r] = rsum;
        }

      // P -> own swizzled LDS slab (stride 64, chunk ^ (row&7); no barrier needed)
#pragma unroll
      for (int mi = 0; mi < 2; mi++)
#pragma unroll
        for (int ni = 0; ni < 4; ni++)
#pragma unroll
          for (int r = 0; r < 4; r++) {
            const int row = mi * 16 + quad * 4 + r;
            Pw[row * 64 + (((ni * 2 + (l16 >> 3)) ^ (row & 7)) << 3) + (l16 & 7)] =
                __float2bfloat16(sacc[mi][ni][r]);
          }

      // O += P @ V
      const bf16* Vcur = VTs[cur];
#pragma unroll
      for (int kc = 0; kc < 2; kc++) {
        short8 pfr[2];
#pragma unroll
        for (int mi = 0; mi < 2; mi++) {
          const int row = mi * 16 + l16;
          pfr[mi] = *(const short8*)(Pw + row * 64 + (((kc * 4 + quad) ^ (row & 7)) << 3));
        }
#pragma unroll
        for (int ni = 0; ni < 8; ni++) {
          short8 vf = *(const short8*)(Vcur + (ni * 16 + l16) * 64 +
                                       (((kc * 4 + quad) ^ (l16 & 7)) << 3));
          __builtin_amdgcn_s_setprio(1);
#pragma unroll
          for (int mi = 0; mi < 2; mi++)
            oacc[mi][ni] = mfma_bf16(pfr[mi], vf, oacc[mi][ni]);
          __builtin_amdgcn_s_setprio(0);
        }
      }

      barrier_f();  // all waves done reading [cur]; next iter may overwrite it
    }

    if (seg == 0) {
      // partial epilogue: un-normalized O (f32) + row sums to workspace slot 'half'
      float* Ob = Opart + (((long)half * 2 + b) * NHEADS + h) * (1024L * 128);
      float* lb = lpart + (((long)half * 2 + b) * NHEADS + h) * 1024L;
#pragma unroll
      for (int mi = 0; mi < 2; mi++)
#pragma unroll
        for (int r = 0; r < 4; r++) {
          float s = lrun[mi][r];
#pragma unroll
          for (int o = 1; o < 16; o <<= 1) s += __shfl_xor(s, o, 64);
          const long r10 = (long)qm0 - 1024 + qseg * 32 + mi * 16 + quad * 4 + r;
          if (l16 == 0) lb[r10] = s;
#pragma unroll
          for (int ni = 0; ni < 8; ni++)
            Ob[r10 * 128 + ni * 16 + l16] = oacc[mi][ni][r];
        }
    } else {
      // full epilogue: reduce row sums, repack O via own P slab, gate, coalesced store
      float inv[2][4];
#pragma unroll
      for (int mi = 0; mi < 2; mi++)
#pragma unroll
        for (int r = 0; r < 4; r++) {
          float s = lrun[mi][r];
#pragma unroll
          for (int o = 1; o < 16; o <<= 1) s += __shfl_xor(s, o, 64);
          inv[mi][r] = 1.0f / s;
        }

#pragma unroll
      for (int h2 = 0; h2 < 2; h2++) {
#pragma unroll
        for (int mi = 0; mi < 2; mi++)
#pragma unroll
          for (int nj = 0; nj < 4; nj++)
#pragma unroll
            for (int r = 0; r < 4; r++) {
              const int row = mi * 16 + quad * 4 + r;
              Pw[row * 64 + (((nj * 2 + (l16 >> 3)) ^ (row & 7)) << 3) + (l16 & 7)] =
                  __float2bfloat16(oacc[mi][h2 * 4 + nj][r] * inv[mi][r]);
            }
#pragma unroll
        for (int i = 0; i < 4; i++) {
          const int lrow = i * 8 + (lane >> 3);
          const int coff = (lane & 7) * 8;
          short8 o8 = *(const short8*)(Pw + lrow * 64 + ((((lane & 7) ^ (lrow & 7))) << 3));
          const long srow = qm0 + qseg * 32 + lrow;
          const bf16* gp = qkv + ((long)b * S_LEN + srow) * QKVN + h * 256 + 128 + h2 * 64 + coff;
          short8 g8 = *(const short8*)gp;
          short8 res;
#pragma unroll
          for (int e = 0; e < 8; e++) {
            float ov = bfbits_to_f(o8[e]);
            float gv = bfbits_to_f(g8[e]);
            res[e] = f_to_bfbits(ov / (1.0f + __expf(-gv)));
          }
          *(short8*)(Aout + ((long)b * S_LEN + srow) * 2048 + h * 128 + h2 * 64 + coff) = res;
        }
      }
    }
  }
}

// ---------------- combine split-K partials for q-rows 1024..2047 ----------------
// O = (O0 + O1) / (l0 + l1), then sigmoid gate, bf16 store to Aout.
__global__ __launch_bounds__(256) void combine_attn(
    const float* __restrict__ Opart, const float* __restrict__ lpart,
    const bf16* __restrict__ qkv, bf16* __restrict__ Aout) {
  const long tid = (long)blockIdx.x * 256 + threadIdx.x;  // [0, 524288)
  const int d0 = ((int)tid & 15) * 8;
  const long rh = tid >> 4;                               // [0, 32768): b*16384+h*1024+r
  const int r = (int)(rh & 1023);
  const int h = (int)((rh >> 10) & 15);
  const int b = (int)(rh >> 14);
  const float inv = 1.0f / (lpart[rh] + lpart[rh + 32768]);
  const float* O0 = Opart + rh * 128 + d0;
  const float* O1 = O0 + 4194304L;  // half-slot stride = 2*16*1024*128
  float4 a0 = *(const float4*)O0;
  float4 a1 = *(const float4*)(O0 + 4);
  float4 c0 = *(const float4*)O1;
  float4 c1 = *(const float4*)(O1 + 4);
  const long srow = 1024 + r;
  const bf16* gp = qkv + ((long)b * S_LEN + srow) * QKVN + h * 256 + 128 + d0;
  short8 g8 = *(const short8*)gp;
  float ov[8] = {a0.x + c0.x, a0.y + c0.y, a0.z + c0.z, a0.w + c0.w,
                 a1.x + c1.x, a1.y + c1.y, a1.z + c1.z, a1.w + c1.w};
  short8 res;
#pragma unroll
  for (int e = 0; e < 8; e++) {
    float gv = bfbits_to_f(g8[e]);
    res[e] = f_to_bfbits(ov[e] * inv / (1.0f + __expf(-gv)));
  }
  *(short8*)(Aout + ((long)b * S_LEN + srow) * 2048 + h * 128 + d0) = res;
}

extern "C" void kernel_launch(void* const* d_in, const int* in_sizes, int n_in,
                              void* d_out, int out_size, void* d_ws, size_t ws_size,
                              hipStream_t stream) {
  const float* hs = (const float*)d_in[0];
  const float* wq = (const float*)d_in[1];
  const float* wk = (const float*)d_in[2];
  const float* wv = (const float*)d_in[3];
  const float* wo = (const float*)d_in[4];
  const float* qnw = (const float*)d_in[5];
  const float* knw = (const float*)d_in[6];
  const float* rcos = (const float*)d_in[7];
  const float* rsin = (const float*)d_in[8];

  float* out = (float*)d_out;                 // (2,2048,2048)
  float* kcache = out + 8388608;              // (2,4,2048,128)
  float* vcache = out + 10485760;             // (2,4,2048,128)

  char* ws = (char*)d_ws;
  bf16* Xb    = (bf16*)(ws);                  // (4096,2048)
  bf16* WqkvT = (bf16*)(ws + 16777216L);      // (5120,2048)
  bf16* WoT   = (bf16*)(ws + 37748736L);      // (2048,2048)
  bf16* QKV   = (bf16*)(ws + 46137344L);      // (4096,5120)
  bf16* Qb    = (bf16*)(ws + 88080384L);      // (2,16,2048,128)
  bf16* Kbq   = (bf16*)(ws + 104857600L);     // (2,4,2048,128)
  bf16* VTb   = (bf16*)(ws + 109051904L);     // (2,4,128,2048)
  bf16* Aout  = (bf16*)(ws + 113246208L);     // (4096,2048)
  // split-K partials: reuse Xb/WqkvT region (dead after the QKV GEMM).
  // Opart [2][2][16][1024][128] f32 = 33,554,432 B; lpart = 262,144 B; end < WoT.
  float* Opart = (float*)(ws);
  float* lpart = (float*)(ws + 33554432L);

  // fused prep: cast hs->Xb + transpose wq/wk/wv->WqkvT + wo->WoT (one launch)
  prep_fused<<<22528, 256, 0, stream>>>(hs, wq, wk, wv, wo, Xb, WqkvT, WoT);

  // QKV GEMM: (4096x2048) x (5120x2048)^T -> 256x320 tiles, grid 16x16 = 256 blocks
  gemm_big<bf16, 256, 320, 3, 2, 2, 2><<<dim3(16, 16), 512, 0, stream>>>(Xb, WqkvT, QKV, 2048, 5120);

  qkv_post<<<4096, 256, 0, stream>>>(QKV, qnw, knw, rcos, rsin, Qb, Kbq, kcache, vcache);

  // V^T (per (b,kv): (2048,128) f32 -> (128,2048) bf16)
  transpose_cast<<<dim3(4, 64, 8), dim3(32, 8), 0, stream>>>(vcache, VTb, 2048, 128,
                                                             2048L * 128, 2048L * 128);

  flash_attn<<<256, 512, 0, stream>>>(Qb, Kbq, VTb, QKV, Aout, Opart, lpart);
  combine_attn<<<2048, 256, 0, stream>>>(Opart, lpart, QKV, Aout);

  // output GEMM: (4096x2048) x (2048x2048)^T -> 128x256 tiles, grid 32x8 = 256 blocks
  gemm_big<float, 128, 256, 2, 2, 1, 1><<<dim3(32, 8), 512, 0, stream>>>(Aout, WoT, out, 2048, 2048);
}